// Round 8
// baseline (398.096 us; speedup 1.0000x reference)
//
#include <hip/hip_runtime.h>

#define NN 100000
#define EE 1200000
#define ALPHA_C 0.2f
#define EPS_C 1e-5f

typedef __attribute__((ext_vector_type(8))) short short8;
typedef __attribute__((ext_vector_type(4))) float f32x4;
#define MFMA __builtin_amdgcn_mfma_f32_16x16x32_bf16

#define PITCH 72  // A-tile LDS pitch (ushorts)

typedef const __attribute__((address_space(1))) unsigned int* gas_t;
typedef __attribute__((address_space(3))) unsigned int* las_t;

// ---------------- bf16 helpers ----------------

__device__ __forceinline__ ushort f2bf(float f) {
  unsigned u = __float_as_uint(f);
  unsigned r = (u + 0x7FFFu + ((u >> 16) & 1u)) >> 16;
  return (ushort)r;
}
__device__ __forceinline__ float bf2f(ushort h) { return __uint_as_float((unsigned)h << 16); }

__device__ __forceinline__ float ftanh(float x) {
  float ax = fabsf(x);
  float e = __expf(2.f * ax);
  float t = 1.f - 2.f / (e + 1.f);
  return copysignf(t, x);
}

// ---------------- CSR build ----------------

__global__ __launch_bounds__(256) void k_zero2(int* __restrict__ a, int* __restrict__ b) {
  int i = blockIdx.x * 256 + threadIdx.x;
  if (i < NN) { a[i] = 0; b[i] = 0; }
}

__global__ __launch_bounds__(256) void k_count(const int* __restrict__ dstv, int* __restrict__ deg) {
  int e = blockIdx.x * 256 + threadIdx.x;
  if (e < EE) atomicAdd(&deg[dstv[e]], 1);
}

__global__ __launch_bounds__(256) void k_scan1(const int* __restrict__ deg, int* __restrict__ rowp,
                                               int* __restrict__ bsum, float* __restrict__ dinv) {
  __shared__ int s[256];
  int t = threadIdx.x;
  int i = blockIdx.x * 256 + t;
  int v = (i < NN) ? deg[i] : 0;
  if (i < NN) dinv[i] = rsqrtf((float)v + 1.0f);
  s[t] = v;
  __syncthreads();
  for (int off = 1; off < 256; off <<= 1) {
    int add = (t >= off) ? s[t - off] : 0;
    __syncthreads();
    s[t] += add;
    __syncthreads();
  }
  if (i < NN) rowp[i] = s[t] - v;
  if (t == 255) bsum[blockIdx.x] = s[255];
}

__global__ __launch_bounds__(512) void k_scan2(int* __restrict__ bsum, int* __restrict__ rowp, int nb) {
  __shared__ int s[512];
  int t = threadIdx.x;
  int v = (t < nb) ? bsum[t] : 0;
  s[t] = v;
  __syncthreads();
  for (int off = 1; off < 512; off <<= 1) {
    int add = (t >= off) ? s[t - off] : 0;
    __syncthreads();
    s[t] += add;
    __syncthreads();
  }
  if (t < nb) bsum[t] = s[t] - v;
  if (t == 0) rowp[NN] = EE;
}

__global__ __launch_bounds__(256) void k_scan3(int* __restrict__ rowp, const int* __restrict__ bsum) {
  int i = blockIdx.x * 256 + threadIdx.x;
  if (i < NN) rowp[i] += bsum[blockIdx.x];
}

__global__ __launch_bounds__(256) void k_fill(const int* __restrict__ srcv, const int* __restrict__ dstv,
                                              const int* __restrict__ rowp, int* __restrict__ fill,
                                              int* __restrict__ col) {
  int e = blockIdx.x * 256 + threadIdx.x;
  if (e < EE) {
    int d = dstv[e];
    int pos = rowp[d] + atomicAdd(&fill[d], 1);
    col[pos] = srcv[e];
  }
}

// ---------------- SpMM ----------------

__global__ __launch_bounds__(256) void k_prescale(const float* __restrict__ feat,
                                                  const float* __restrict__ dinv,
                                                  float* __restrict__ xs) {
  int idx = blockIdx.x * 256 + threadIdx.x;
  if (idx < NN * 16) {
    float4 v = ((const float4*)feat)[idx];
    float d = dinv[idx >> 4];
    v.x *= d; v.y *= d; v.z *= d; v.w *= d;
    ((float4*)xs)[idx] = v;
  }
}

__global__ __launch_bounds__(256) void k_spmm(const float4* __restrict__ xs4, const float* __restrict__ dinv,
                                              const int* __restrict__ rowp, const int* __restrict__ col,
                                              float4* __restrict__ out4) {
  int node = blockIdx.x * 16 + (threadIdx.x >> 4);
  int q = threadIdx.x & 15;
  if (node >= NN) return;
  int s = rowp[node], e = rowp[node + 1];
  float4 a0 = {0.f, 0.f, 0.f, 0.f}, a1 = a0, a2 = a0, a3 = a0;
  int j = s;
  for (; j + 4 <= e; j += 4) {
    int c0 = col[j], c1 = col[j + 1], c2 = col[j + 2], c3 = col[j + 3];
    float4 v0 = xs4[c0 * 16 + q];
    float4 v1 = xs4[c1 * 16 + q];
    float4 v2 = xs4[c2 * 16 + q];
    float4 v3 = xs4[c3 * 16 + q];
    a0 += v0; a1 += v1; a2 += v2; a3 += v3;
  }
  for (; j < e; ++j) a0 += xs4[col[j] * 16 + q];
  float4 sv = xs4[node * 16 + q];
  float d = dinv[node];
  float4 o;
  o.x = d * (a0.x + a1.x + a2.x + a3.x + sv.x);
  o.y = d * (a0.y + a1.y + a2.y + a3.y + sv.y);
  o.z = d * (a0.z + a1.z + a2.z + a3.z + sv.z);
  o.w = d * (a0.w + a1.w + a2.w + a3.w + sv.w);
  out4[node * 16 + q] = o;
}

// ---------------- weight pre-pack (B-fragment order, hi||lo bf16) ----------------

__global__ __launch_bounds__(256) void k_pack(const float* __restrict__ Wh, const float* __restrict__ Wx,
                                              const float* __restrict__ ff1w, const float* __restrict__ ff2w,
                                              const float* __restrict__ c1w, const float* __restrict__ c2w,
                                              ushort* __restrict__ wpk) {
  int id = blockIdx.x;
  const float* src;
  int ncol = 64, vcol = 64;
  if (id < 8) src = Wx + id * 4096;
  else if (id < 16) src = Wh + (id - 8) * 4096;
  else if (id < 18) src = ff1w + (id - 16) * 4096;
  else if (id < 20) src = ff2w + (id - 18) * 4096;
  else if (id == 20) src = c1w;
  else { src = c2w; ncol = 40; vcol = 40; }
  ushort* dst = wpk + (size_t)id * 8192;
  for (int p = threadIdx.x; p < 512; p += 256) {
    int f = p >> 6, l = p & 63;
    int kh = f & 1, tc = f >> 1;
    int r0 = 32 * kh + 8 * (l >> 4), c = 16 * tc + (l & 15);
#pragma unroll
    for (int j = 0; j < 8; ++j) {
      float v = (c < vcol) ? src[(r0 + j) * ncol + c] : 0.f;
      ushort h = f2bf(v);
      dst[f * 512 + l * 8 + j] = h;
      dst[4096 + f * 512 + l * 8 + j] = f2bf(v - bf2f(h));
    }
  }
}

// ---------------- dense helpers ----------------

__device__ __forceinline__ float red16(float v) {
  v += __shfl_xor(v, 1);
  v += __shfl_xor(v, 2);
  v += __shfl_xor(v, 4);
  v += __shfl_xor(v, 8);
  return v;
}

__device__ __forceinline__ void stage_tile(const float* __restrict__ src, int gbase,
                                           ushort* __restrict__ hi, ushort* __restrict__ lo, int t) {
#pragma unroll
  for (int u = 0; u < 4; ++u) {
    int f = u * 256 + t;
    int row = f >> 4, c4 = (f & 15) << 2;
    int gr = gbase + row;
    if (gr > NN - 1) gr = NN - 1;
    float4 v = *(const float4*)(src + gr * 64 + c4);
    ushort h0 = f2bf(v.x), h1 = f2bf(v.y), h2 = f2bf(v.z), h3 = f2bf(v.w);
    ushort l0 = f2bf(v.x - bf2f(h0)), l1 = f2bf(v.y - bf2f(h1)),
           l2 = f2bf(v.z - bf2f(h2)), l3 = f2bf(v.w - bf2f(h3));
    int o = row * PITCH + c4;
    *(ushort4*)(hi + o) = make_ushort4(h0, h1, h2, h3);
    *(ushort4*)(lo + o) = make_ushort4(l0, l1, l2, l3);
  }
}

// async stage of one packed matmul (16KB) global -> LDS (linear, wave-uniform dest base)
__device__ __forceinline__ void issueB(const ushort* __restrict__ wp, ushort* buf, int t) {
  const int lane = t & 63, w = t >> 6;
  const char* g = (const char*)wp;
  char* b = (char*)buf;
  const int wo = w * 4096;
#pragma unroll
  for (int u = 0; u < 4; ++u) {
    __builtin_amdgcn_global_load_lds((gas_t)(g + wo + u * 1024 + lane * 16),
                                     (las_t)(b + wo + u * 1024), 16, 0, 0);
  }
}

// cooperative sync copy (used by k_clf)
__device__ __forceinline__ void stageB(const ushort* __restrict__ wp, ushort* __restrict__ bsta, int t) {
#pragma unroll
  for (int u = 0; u < 4; ++u) {
    int o = (u * 256 + t) * 8;
    *(short8*)(bsta + o) = *(const short8*)(wp + o);
  }
}

// split-precision MFMA: A-frags in regs, B-frags from LDS
template <int NT>
__device__ __forceinline__ void mm_mfma_l(short8 a0h, short8 a1h, short8 a0l, short8 a1l,
                                          const ushort* __restrict__ bsta, int l, f32x4* C) {
#pragma unroll
  for (int tc = 0; tc < NT; ++tc) {
#pragma unroll
    for (int kh = 0; kh < 2; ++kh) {
      const short8 bh = *(const short8*)(bsta + (tc * 2 + kh) * 512 + l * 8);
      const short8 bl = *(const short8*)(bsta + 4096 + (tc * 2 + kh) * 512 + l * 8);
      const short8 ah = kh ? a1h : a0h;
      const short8 alo = kh ? a1l : a0l;
      C[tc] = MFMA(ah, bh, C[tc], 0, 0, 0);
      C[tc] = MFMA(ah, bl, C[tc], 0, 0, 0);
      C[tc] = MFMA(alo, bh, C[tc], 0, 0, 0);
    }
  }
}

__device__ __forceinline__ void ln_frag(float v[4][4]) {
#pragma unroll
  for (int r = 0; r < 4; ++r) {
    float s = v[0][r] + v[1][r] + v[2][r] + v[3][r];
    s = red16(s);
    float mu = s * 0.015625f;
    float q = 0.f;
#pragma unroll
    for (int tc = 0; tc < 4; ++tc) { float d = v[tc][r] - mu; q = fmaf(d, d, q); }
    q = red16(q);
    float inv = rsqrtf(q * 0.015625f + EPS_C);
#pragma unroll
    for (int tc = 0; tc < 4; ++tc) v[tc][r] = (v[tc][r] - mu) * inv;
  }
}

// ---------------- fused per-layer kernel (issue-early 2-phase pipeline) ----------------
// 64 nodes/block, 4 waves. A-frags in regs; B double-buffered in LDS; prefetch for the
// NEXT phase issued right after the previous __syncthreads, consumed after the next one.
// Every phase boundary is a full __syncthreads (vmcnt(0) drain) — correct by construction.

template <int HAS_H, int WSC>
__global__ __launch_bounds__(256) void k_layer(
    const float* __restrict__ aggX, const float* __restrict__ aggH,
    const float* __restrict__ h_in, float* __restrict__ h_out,
    float* __restrict__ hs_out, const float* __restrict__ dinv,
    const ushort* __restrict__ wxp, const ushort* __restrict__ whp,
    const float* __restrict__ bxl, const float* __restrict__ bhl,
    const float* __restrict__ gfw, const float* __restrict__ gfb,
    const float* __restrict__ guw, const float* __restrict__ gub,
    const ushort* __restrict__ ff1p, const float* __restrict__ ff1b,
    const ushort* __restrict__ ff2p, const float* __restrict__ ff2b) {
  __shared__ __align__(16) ushort th[64 * PITCH], tl[64 * PITCH];
  __shared__ __align__(16) ushort bsta[2][8192];
  const int t = threadIdx.x, blk = blockIdx.x;
  const int w = t >> 6, l = t & 63, lg = l >> 4, lr = l & 15;
  const int abase = (16 * w + lr) * PITCH + 8 * lg;

  issueB(wxp, bsta[0], t);  // prefetch Wx k=0 (drained by stage_tile's barrier)

  stage_tile(aggX, blk * 64, th, tl, t);
  __syncthreads();
  short8 xa0h = *(const short8*)(th + abase);
  short8 xa1h = *(const short8*)(th + abase + 32);
  short8 xa0l = *(const short8*)(tl + abase);
  short8 xa1l = *(const short8*)(tl + abase + 32);
  short8 ha0h = (short8)0, ha1h = (short8)0, ha0l = (short8)0, ha1l = (short8)0;
  if (HAS_H) {
    __syncthreads();
    stage_tile(aggH, blk * 64, th, tl, t);
    __syncthreads();
    ha0h = *(const short8*)(th + abase);
    ha1h = *(const short8*)(th + abase + 32);
    ha0l = *(const short8*)(tl + abase);
    ha1l = *(const short8*)(tl + abase + 32);
  }

  float gfhw[4], gfxw[4], guhw[4], guxw[4];
  float bxv[4][4], bhv[4][4];
#pragma unroll
  for (int tc = 0; tc < 4; ++tc) {
    gfhw[tc] = gfw[lr + 16 * tc]; gfxw[tc] = gfw[64 + lr + 16 * tc];
    guhw[tc] = guw[lr + 16 * tc]; guxw[tc] = guw[64 + lr + 16 * tc];
#pragma unroll
    for (int k = 0; k < 4; ++k) {
      bxv[k][tc] = bxl[k * 64 + lr + 16 * tc];
      bhv[k][tc] = bhl[k * 64 + lr + 16 * tc];
    }
  }
  const float gfb0 = gfb[0], gub0 = gub[0];

  float acc[4][4];
#pragma unroll
  for (int tc = 0; tc < 4; ++tc)
#pragma unroll
    for (int r = 0; r < 4; ++r) acc[tc][r] = 0.f;

  // ---- phase loop: issue-early prefetch + one __syncthreads per phase ----
#pragma unroll
  for (int k = 0; k < 4; ++k) {
    f32x4 cx[4], ch[4];
#pragma unroll
    for (int tc = 0; tc < 4; ++tc) { cx[tc] = (f32x4)0.f; ch[tc] = (f32x4)0.f; }

    if (HAS_H) {
      // X phase: b1 free (fenced by prev-iter barrier); issue Wh_k early, consume b0
      issueB(whp + k * 8192, bsta[1], t);
      mm_mfma_l<4>(xa0h, xa1h, xa0l, xa1l, bsta[0], l, cx);
      __syncthreads();  // drains Wh_k; all waves done reading b0
      // H phase: issue next-X (or FF1) early into b0, consume b1
      issueB(k < 3 ? (wxp + (k + 1) * 8192) : ff1p, bsta[0], t);
      mm_mfma_l<4>(ha0h, ha1h, ha0l, ha1l, bsta[1], l, ch);
    } else {
      issueB(k < 3 ? (wxp + (k + 1) * 8192) : ff1p, bsta[(k + 1) & 1], t);
      mm_mfma_l<4>(xa0h, xa1h, xa0l, xa1l, bsta[k & 1], l, cx);
    }

    float Cx[4][4], Ch[4][4];
#pragma unroll
    for (int tc = 0; tc < 4; ++tc)
#pragma unroll
      for (int r = 0; r < 4; ++r) {
        Cx[tc][r] = cx[tc][r] + bxv[k][tc];
        Ch[tc][r] = (HAS_H ? ch[tc][r] : 0.f) + bhv[k][tc];
      }
#pragma unroll
    for (int r = 0; r < 4; ++r) {
      float pf = 0.f, pu = 0.f;
#pragma unroll
      for (int tc = 0; tc < 4; ++tc) {
        pf = fmaf(Ch[tc][r], gfhw[tc], pf); pf = fmaf(Cx[tc][r], gfxw[tc], pf);
        pu = fmaf(Ch[tc][r], guhw[tc], pu); pu = fmaf(Cx[tc][r], guxw[tc], pu);
      }
      pf = red16(pf); pu = red16(pu);
      float fv = ALPHA_C * ftanh(pf + gfb0);
      float uv = ALPHA_C * ftanh(pu + gub0);
#pragma unroll
      for (int tc = 0; tc < 4; ++tc)
        acc[tc][r] += (1.f + fv) * Ch[tc][r] + (1.f + uv) * Cx[tc][r];
    }
    __syncthreads();  // drains this phase's prefetch; fences consumed buffer
  }
  // here: bsta[0] = FF1 (drained); bsta[1] free

  // hmid = acc/4 + h_in ; LN
  float hmid[4][4];
#pragma unroll
  for (int tc = 0; tc < 4; ++tc)
#pragma unroll
    for (int r = 0; r < 4; ++r) {
      float hv = 0.f;
      if (HAS_H) {
        int gn = blk * 64 + 16 * w + 4 * lg + r;
        if (gn > NN - 1) gn = NN - 1;
        hv = h_in[gn * 64 + lr + 16 * tc];
      }
      hmid[tc][r] = fmaf(acc[tc][r], 0.25f, hv);
    }
  ln_frag(hmid);

  issueB(ff2p, bsta[1], t);  // b1 fenced by loop-final barrier
#pragma unroll
  for (int tc = 0; tc < 4; ++tc)
#pragma unroll
    for (int r = 0; r < 4; ++r) {
      int o = (16 * w + 4 * lg + r) * PITCH + lr + 16 * tc;
      ushort h = f2bf(hmid[tc][r]);
      th[o] = h;
      tl[o] = f2bf(hmid[tc][r] - bf2f(h));
    }
  __syncthreads();  // hmid visible; FF2 loads drained
  short8 m0h = *(const short8*)(th + abase);
  short8 m1h = *(const short8*)(th + abase + 32);
  short8 m0l = *(const short8*)(tl + abase);
  short8 m1l = *(const short8*)(tl + abase + 32);

  f32x4 f1[4];
#pragma unroll
  for (int tc = 0; tc < 4; ++tc) f1[tc] = (f32x4)0.f;
  mm_mfma_l<4>(m0h, m1h, m0l, m1l, bsta[0], l, f1);
  float F1[4][4];
#pragma unroll
  for (int tc = 0; tc < 4; ++tc) {
    float bv = ff1b[lr + 16 * tc];
#pragma unroll
    for (int r = 0; r < 4; ++r) F1[tc][r] = fmaxf(f1[tc][r] + bv, 0.f);
  }
  __syncthreads();  // all waves' m-frag reads consumed by their MFMAs before this point
#pragma unroll
  for (int tc = 0; tc < 4; ++tc)
#pragma unroll
    for (int r = 0; r < 4; ++r) {
      int o = (16 * w + 4 * lg + r) * PITCH + lr + 16 * tc;
      ushort h = f2bf(F1[tc][r]);
      th[o] = h;
      tl[o] = f2bf(F1[tc][r] - bf2f(h));
    }
  __syncthreads();  // F1 visible
  short8 g0h = *(const short8*)(th + abase);
  short8 g1h = *(const short8*)(th + abase + 32);
  short8 g0l = *(const short8*)(tl + abase);
  short8 g1l = *(const short8*)(tl + abase + 32);

  f32x4 f2[4];
#pragma unroll
  for (int tc = 0; tc < 4; ++tc) f2[tc] = (f32x4)0.f;
  mm_mfma_l<4>(g0h, g1h, g0l, g1l, bsta[1], l, f2);
  float F2[4][4];
#pragma unroll
  for (int tc = 0; tc < 4; ++tc) {
    float bv = ff2b[lr + 16 * tc];
#pragma unroll
    for (int r = 0; r < 4; ++r) F2[tc][r] = f2[tc][r] + bv + hmid[tc][r];
  }
  ln_frag(F2);

#pragma unroll
  for (int r = 0; r < 4; ++r) {
    int gn = blk * 64 + 16 * w + 4 * lg + r;
    if (gn < NN) {
      float dv = WSC ? dinv[gn] : 0.f;
#pragma unroll
      for (int tc = 0; tc < 4; ++tc) {
        h_out[gn * 64 + lr + 16 * tc] = F2[tc][r];
        if (WSC) hs_out[gn * 64 + lr + 16 * tc] = F2[tc][r] * dv;
      }
    }
  }
}

// ---------------- classifier (round-6 structure, known-good) ----------------

__global__ __launch_bounds__(256) void k_clf(const float* __restrict__ h,
                                             const ushort* __restrict__ c1p, const float* __restrict__ b1,
                                             const ushort* __restrict__ c2p, const float* __restrict__ b2,
                                             float* __restrict__ outv) {
  __shared__ __align__(16) ushort th[64 * PITCH], tl[64 * PITCH];
  __shared__ __align__(16) ushort bsta[8192];
  const int t = threadIdx.x, blk = blockIdx.x;
  const int w = t >> 6, l = t & 63, lg = l >> 4, lr = l & 15;
  const int abase = (16 * w + lr) * PITCH + 8 * lg;

  stage_tile(h, blk * 64, th, tl, t);
  __syncthreads();
  short8 a0h = *(const short8*)(th + abase);
  short8 a1h = *(const short8*)(th + abase + 32);
  short8 a0l = *(const short8*)(tl + abase);
  short8 a1l = *(const short8*)(tl + abase + 32);

  f32x4 c1[4];
#pragma unroll
  for (int tc = 0; tc < 4; ++tc) c1[tc] = (f32x4)0.f;
  stageB(c1p, bsta, t);
  __syncthreads();
  mm_mfma_l<4>(a0h, a1h, a0l, a1l, bsta, l, c1);
  __syncthreads();
#pragma unroll
  for (int tc = 0; tc < 4; ++tc) {
    float bv = b1[lr + 16 * tc];
#pragma unroll
    for (int r = 0; r < 4; ++r) {
      float v = fmaxf(c1[tc][r] + bv, 0.f);
      int o = (16 * w + 4 * lg + r) * PITCH + lr + 16 * tc;
      ushort hh = f2bf(v);
      th[o] = hh;
      tl[o] = f2bf(v - bf2f(hh));
    }
  }
  stageB(c2p, bsta, t);
  __syncthreads();
  short8 m0h = *(const short8*)(th + abase);
  short8 m1h = *(const short8*)(th + abase + 32);
  short8 m0l = *(const short8*)(tl + abase);
  short8 m1l = *(const short8*)(tl + abase + 32);

  f32x4 c2[3];
#pragma unroll
  for (int tc = 0; tc < 3; ++tc) c2[tc] = (f32x4)0.f;
  mm_mfma_l<3>(m0h, m1h, m0l, m1l, bsta, l, c2);
#pragma unroll
  for (int tc = 0; tc < 3; ++tc) {
    int cc = lr + 16 * tc;
    if (cc < 40) {
      float bv = b2[cc];
#pragma unroll
      for (int r = 0; r < 4; ++r) {
        int gn = blk * 64 + 16 * w + 4 * lg + r;
        if (gn < NN) outv[gn * 40 + cc] = c2[tc][r] + bv;
      }
    }
  }
}

// ---------------- launch ----------------

extern "C" void kernel_launch(void* const* d_in, const int* in_sizes, int n_in,
                              void* d_out, int out_size, void* d_ws, size_t ws_size,
                              hipStream_t stream) {
  (void)in_sizes; (void)n_in; (void)out_size; (void)ws_size;
  const float* x    = (const float*)d_in[0];
  const int*   ei   = (const int*)d_in[1];
  const float* Wh   = (const float*)d_in[2];
  const float* bh   = (const float*)d_in[3];
  const float* Wx   = (const float*)d_in[4];
  const float* bx   = (const float*)d_in[5];
  const float* gfw  = (const float*)d_in[6];
  const float* gfb  = (const float*)d_in[7];
  const float* guw  = (const float*)d_in[8];
  const float* gub  = (const float*)d_in[9];
  const float* ff1w = (const float*)d_in[10];
  const float* ff1b = (const float*)d_in[11];
  const float* ff2w = (const float*)d_in[12];
  const float* ff2b = (const float*)d_in[13];
  const float* c1w  = (const float*)d_in[14];
  const float* c1b  = (const float*)d_in[15];
  const float* c2w  = (const float*)d_in[16];
  const float* c2b  = (const float*)d_in[17];
  float* outv = (float*)d_out;

  char* ws = (char*)d_ws;
  size_t o = 0;
  auto take = [&](size_t b) { char* p = ws + o; o += (b + 255) & ~(size_t)255; return p; };
  int*    deg  = (int*)take((size_t)NN * 4);
  int*    fill = (int*)take((size_t)NN * 4);
  int*    rowp = (int*)take((size_t)(NN + 1) * 4);
  int*    bsum = (int*)take(512 * 4);
  int*    col  = (int*)take((size_t)EE * 4);
  float*  dinv = (float*)take((size_t)NN * 4);
  ushort* wpk  = (ushort*)take((size_t)22 * 8192 * 2);
  float*  aggX = (float*)take((size_t)NN * 64 * 4);
  float*  aggH = (float*)take((size_t)NN * 64 * 4);
  float*  hbuf = (float*)take((size_t)NN * 64 * 4);
  float*  xsc  = (float*)take((size_t)NN * 64 * 4);

  const int* srcv = ei;
  const int* dstv = ei + EE;

  const int NB_E = (EE + 255) / 256;
  const int NB_N = (NN + 255) / 256;
  const int NB_V4 = (NN * 16 + 255) / 256;

  k_pack<<<22, 256, 0, stream>>>(Wh, Wx, ff1w, ff2w, c1w, c2w, wpk);
  k_zero2<<<NB_N, 256, 0, stream>>>(deg, fill);
  k_count<<<NB_E, 256, 0, stream>>>(dstv, deg);
  k_scan1<<<NB_N, 256, 0, stream>>>(deg, rowp, bsum, dinv);
  k_scan2<<<1, 512, 0, stream>>>(bsum, rowp, NB_N);
  k_scan3<<<NB_N, 256, 0, stream>>>(rowp, bsum);
  k_fill<<<NB_E, 256, 0, stream>>>(srcv, dstv, rowp, fill, col);

  // AggX
  k_prescale<<<NB_V4, 256, 0, stream>>>(x, dinv, xsc);
  k_spmm<<<(NN + 15) / 16, 256, 0, stream>>>((const float4*)xsc, dinv, rowp, col, (float4*)aggX);

  const int NB_L = (NN + 63) / 64;
  // layer 0 (h=0); writes h1 and h1*dinv (into xsc)
  k_layer<0, 1><<<NB_L, 256, 0, stream>>>(
      aggX, aggX, hbuf, hbuf, xsc, dinv,
      wpk + 0 * 8192, wpk + 8 * 8192, bx, bh, gfw, gfb, guw, gub,
      wpk + 16 * 8192, ff1b, wpk + 18 * 8192, ff2b);

  // AggH
  k_spmm<<<(NN + 15) / 16, 256, 0, stream>>>((const float4*)xsc, dinv, rowp, col, (float4*)aggH);

  // layer 1
  k_layer<1, 0><<<NB_L, 256, 0, stream>>>(
      aggX, aggH, hbuf, hbuf, xsc, dinv,
      wpk + 4 * 8192, wpk + 12 * 8192, bx + 256, bh + 256, gfw, gfb, guw, gub,
      wpk + 17 * 8192, ff1b + 64, wpk + 19 * 8192, ff2b + 64);

  k_clf<<<NB_L, 256, 0, stream>>>(hbuf, wpk + 20 * 8192, c1b, wpk + 21 * 8192, c2b, outv);
}

// Round 11
// 380.859 us; speedup vs baseline: 1.0453x; 1.0453x over previous
//
#include <hip/hip_runtime.h>

#define NN 100000
#define EE 1200000
#define ALPHA_C 0.2f
#define EPS_C 1e-5f

typedef __attribute__((ext_vector_type(8))) short short8;
typedef __attribute__((ext_vector_type(4))) float f32x4;
#define MFMA __builtin_amdgcn_mfma_f32_16x16x32_bf16

#define PITCH 72  // A-tile LDS pitch (ushorts): 144B rows, 16B-aligned frags

// ---------------- bf16 helpers ----------------

__device__ __forceinline__ ushort f2bf(float f) {
  unsigned u = __float_as_uint(f);
  unsigned r = (u + 0x7FFFu + ((u >> 16) & 1u)) >> 16;
  return (ushort)r;
}
__device__ __forceinline__ float bf2f(ushort h) { return __uint_as_float((unsigned)h << 16); }

__device__ __forceinline__ float ftanh(float x) {  // validated (round 8 pass)
  float ax = fabsf(x);
  float e = __expf(2.f * ax);
  float t = 1.f - 2.f / (e + 1.f);
  return copysignf(t, x);
}

// ---------------- CSR build ----------------

__global__ __launch_bounds__(256) void k_count(const int* __restrict__ dstv, int* __restrict__ deg) {
  int e = blockIdx.x * 256 + threadIdx.x;
  if (e < EE) atomicAdd(&deg[dstv[e]], 1);
}

__global__ __launch_bounds__(256) void k_scan1(const int* __restrict__ deg, int* __restrict__ rowp,
                                               int* __restrict__ bsum, float* __restrict__ dinv) {
  __shared__ int s[256];
  int t = threadIdx.x;
  int i = blockIdx.x * 256 + t;
  int v = (i < NN) ? deg[i] : 0;
  if (i < NN) dinv[i] = rsqrtf((float)v + 1.0f);  // +1 self-loop
  s[t] = v;
  __syncthreads();
  for (int off = 1; off < 256; off <<= 1) {
    int add = (t >= off) ? s[t - off] : 0;
    __syncthreads();
    s[t] += add;
    __syncthreads();
  }
  if (i < NN) rowp[i] = s[t] - v;
  if (t == 255) bsum[blockIdx.x] = s[255];
}

__global__ __launch_bounds__(512) void k_scan2(int* __restrict__ bsum, int* __restrict__ rowp, int nb) {
  __shared__ int s[512];
  int t = threadIdx.x;
  int v = (t < nb) ? bsum[t] : 0;
  s[t] = v;
  __syncthreads();
  for (int off = 1; off < 512; off <<= 1) {
    int add = (t >= off) ? s[t - off] : 0;
    __syncthreads();
    s[t] += add;
    __syncthreads();
  }
  if (t < nb) bsum[t] = s[t] - v;
  if (t == 0) rowp[NN] = EE;
}

__global__ __launch_bounds__(256) void k_scan3(int* __restrict__ rowp, const int* __restrict__ bsum) {
  int i = blockIdx.x * 256 + threadIdx.x;
  if (i < NN) rowp[i] += bsum[blockIdx.x];
}

__global__ __launch_bounds__(256) void k_fill(const int* __restrict__ srcv, const int* __restrict__ dstv,
                                              const int* __restrict__ rowp, int* __restrict__ fill,
                                              int* __restrict__ col) {
  int e = blockIdx.x * 256 + threadIdx.x;
  if (e < EE) {
    int d = dstv[e];
    int pos = rowp[d] + atomicAdd(&fill[d], 1);
    col[pos] = srcv[e];
  }
}

// ---------------- SpMM ----------------

__global__ __launch_bounds__(256) void k_prescale(const float* __restrict__ feat,
                                                  const float* __restrict__ dinv,
                                                  float* __restrict__ xs) {
  int idx = blockIdx.x * 256 + threadIdx.x;
  if (idx < NN * 16) {
    float4 v = ((const float4*)feat)[idx];
    float d = dinv[idx >> 4];
    v.x *= d; v.y *= d; v.z *= d; v.w *= d;
    ((float4*)xs)[idx] = v;
  }
}

__global__ __launch_bounds__(256) void k_spmm(const float4* __restrict__ xs4, const float* __restrict__ dinv,
                                              const int* __restrict__ rowp, const int* __restrict__ col,
                                              float4* __restrict__ out4) {
  int node = blockIdx.x * 16 + (threadIdx.x >> 4);
  int q = threadIdx.x & 15;
  if (node >= NN) return;
  int s = rowp[node], e = rowp[node + 1];
  float4 a0 = {0.f, 0.f, 0.f, 0.f}, a1 = a0, a2 = a0, a3 = a0;
  int j = s;
  for (; j + 4 <= e; j += 4) {
    int c0 = col[j], c1 = col[j + 1], c2 = col[j + 2], c3 = col[j + 3];
    float4 v0 = xs4[c0 * 16 + q];
    float4 v1 = xs4[c1 * 16 + q];
    float4 v2 = xs4[c2 * 16 + q];
    float4 v3 = xs4[c3 * 16 + q];
    a0 += v0; a1 += v1; a2 += v2; a3 += v3;
  }
  for (; j < e; ++j) a0 += xs4[col[j] * 16 + q];
  float4 sv = xs4[node * 16 + q];
  float d = dinv[node];
  float4 o;
  o.x = d * (a0.x + a1.x + a2.x + a3.x + sv.x);
  o.y = d * (a0.y + a1.y + a2.y + a3.y + sv.y);
  o.z = d * (a0.z + a1.z + a2.z + a3.z + sv.z);
  o.w = d * (a0.w + a1.w + a2.w + a3.w + sv.w);
  out4[node * 16 + q] = o;
}

// ---------------- weight pre-pack (B-fragment order, hi||lo bf16) + deg/fill zero ----
// frag f = tc*2+kh; lane l, j: value = W[32*kh + 8*(l>>4) + j][16*tc + (l&15)]
// ids: 0..7 Wx(l*4+k), 8..15 Wh, 16..17 ff1, 18..19 ff2, 20 clf1, 21 clf2(64x40 pad)

__global__ __launch_bounds__(256) void k_packz(const float* __restrict__ Wh, const float* __restrict__ Wx,
                                               const float* __restrict__ ff1w, const float* __restrict__ ff2w,
                                               const float* __restrict__ c1w, const float* __restrict__ c2w,
                                               ushort* __restrict__ wpk,
                                               int* __restrict__ deg, int* __restrict__ fill) {
  int i = blockIdx.x * 256 + threadIdx.x;
  if (i < NN) { deg[i] = 0; fill[i] = 0; }
  int id = blockIdx.x;
  if (id >= 22) return;
  const float* src;
  int ncol = 64, vcol = 64;
  if (id < 8) src = Wx + id * 4096;
  else if (id < 16) src = Wh + (id - 8) * 4096;
  else if (id < 18) src = ff1w + (id - 16) * 4096;
  else if (id < 20) src = ff2w + (id - 18) * 4096;
  else if (id == 20) src = c1w;
  else { src = c2w; ncol = 40; vcol = 40; }
  ushort* dst = wpk + (size_t)id * 8192;
  for (int p = threadIdx.x; p < 512; p += 256) {
    int f = p >> 6, l = p & 63;
    int kh = f & 1, tc = f >> 1;
    int r0 = 32 * kh + 8 * (l >> 4), c = 16 * tc + (l & 15);
#pragma unroll
    for (int j = 0; j < 8; ++j) {
      float v = (c < vcol) ? src[(r0 + j) * ncol + c] : 0.f;
      ushort h = f2bf(v);
      dst[f * 512 + l * 8 + j] = h;
      dst[4096 + f * 512 + l * 8 + j] = f2bf(v - bf2f(h));
    }
  }
}

// ---------------- dense helpers ----------------

__device__ __forceinline__ float red16(float v) {
  v += __shfl_xor(v, 1);
  v += __shfl_xor(v, 2);
  v += __shfl_xor(v, 4);
  v += __shfl_xor(v, 8);
  return v;
}

// stage a [64 nodes][64 ch] f32 tile into LDS bf16 hi/lo, pitch PITCH
__device__ __forceinline__ void stage_tile(const float* __restrict__ src, int gbase,
                                           ushort* __restrict__ hi, ushort* __restrict__ lo, int t) {
#pragma unroll
  for (int u = 0; u < 4; ++u) {
    int f = u * 256 + t;
    int row = f >> 4, c4 = (f & 15) << 2;
    int gr = gbase + row;
    if (gr > NN - 1) gr = NN - 1;
    float4 v = *(const float4*)(src + gr * 64 + c4);
    ushort h0 = f2bf(v.x), h1 = f2bf(v.y), h2 = f2bf(v.z), h3 = f2bf(v.w);
    ushort l0 = f2bf(v.x - bf2f(h0)), l1 = f2bf(v.y - bf2f(h1)),
           l2 = f2bf(v.z - bf2f(h2)), l3 = f2bf(v.w - bf2f(h3));
    int o = row * PITCH + c4;
    *(ushort4*)(hi + o) = make_ushort4(h0, h1, h2, h3);
    *(ushort4*)(lo + o) = make_ushort4(l0, l1, l2, l3);
  }
}

// cooperative sync copy of one packed matmul (8192 ushort = 16KB) global -> LDS
__device__ __forceinline__ void stageB(const ushort* __restrict__ wp, ushort* __restrict__ bsta, int t) {
#pragma unroll
  for (int u = 0; u < 4; ++u) {
    int o = (u * 256 + t) * 8;
    *(short8*)(bsta + o) = *(const short8*)(wp + o);
  }
}

// split-precision MFMA: A-frags in regs, B-frags from LDS (staged packed matmul)
template <int NT>
__device__ __forceinline__ void mm_mfma_l(short8 a0h, short8 a1h, short8 a0l, short8 a1l,
                                          const ushort* __restrict__ bsta, int l, f32x4* C) {
#pragma unroll
  for (int tc = 0; tc < NT; ++tc) {
#pragma unroll
    for (int kh = 0; kh < 2; ++kh) {
      const short8 bh = *(const short8*)(bsta + (tc * 2 + kh) * 512 + l * 8);
      const short8 bl = *(const short8*)(bsta + 4096 + (tc * 2 + kh) * 512 + l * 8);
      const short8 ah = kh ? a1h : a0h;
      const short8 alo = kh ? a1l : a0l;
      C[tc] = MFMA(ah, bh, C[tc], 0, 0, 0);
      C[tc] = MFMA(ah, bl, C[tc], 0, 0, 0);
      C[tc] = MFMA(alo, bh, C[tc], 0, 0, 0);
    }
  }
}

__device__ __forceinline__ void ln_frag(float v[4][4]) {
#pragma unroll
  for (int r = 0; r < 4; ++r) {
    float s = v[0][r] + v[1][r] + v[2][r] + v[3][r];
    s = red16(s);
    float mu = s * 0.015625f;
    float q = 0.f;
#pragma unroll
    for (int tc = 0; tc < 4; ++tc) { float d = v[tc][r] - mu; q = fmaf(d, d, q); }
    q = red16(q);
    float inv = rsqrtf(q * 0.015625f + EPS_C);
#pragma unroll
    for (int tc = 0; tc < 4; ++tc) v[tc][r] = (v[tc][r] - mu) * inv;
  }
}

// ---------------- fused per-layer kernel (round-5 proven structure) ----------------
// 64 nodes/block, 4 waves; wave w rows 16w..16w+15 (all tile traffic strip-local).
// A-frags in regs; B via sync LDS stage. DO_CLF=1 appends classifier, writes outv.
// C/D frag: row = 16w + 4*(l>>4) + r, col = (l&15) + 16*tc.

template <int HAS_H, int WSC, int DO_CLF>
__global__ __launch_bounds__(256) void k_layer(
    const float* __restrict__ aggX, const float* __restrict__ aggH,
    const float* __restrict__ h_in, float* __restrict__ h_out,
    float* __restrict__ hs_out, const float* __restrict__ dinv,
    const ushort* __restrict__ wxp, const ushort* __restrict__ whp,
    const float* __restrict__ bxl, const float* __restrict__ bhl,
    const float* __restrict__ gfw, const float* __restrict__ gfb,
    const float* __restrict__ guw, const float* __restrict__ gub,
    const ushort* __restrict__ ff1p, const float* __restrict__ ff1b,
    const ushort* __restrict__ ff2p, const float* __restrict__ ff2b,
    const ushort* __restrict__ c1p, const float* __restrict__ c1b,
    const ushort* __restrict__ c2p, const float* __restrict__ c2b,
    float* __restrict__ outv) {
  __shared__ __align__(16) ushort th[64 * PITCH], tl[64 * PITCH];
  __shared__ __align__(16) ushort bsta[8192];
  const int t = threadIdx.x, blk = blockIdx.x;
  const int w = t >> 6, l = t & 63, lg = l >> 4, lr = l & 15;
  const int abase = (16 * w + lr) * PITCH + 8 * lg;

  stage_tile(aggX, blk * 64, th, tl, t);
  __syncthreads();
  short8 xa0h = *(const short8*)(th + abase);
  short8 xa1h = *(const short8*)(th + abase + 32);
  short8 xa0l = *(const short8*)(tl + abase);
  short8 xa1l = *(const short8*)(tl + abase + 32);
  short8 ha0h = (short8)0, ha1h = (short8)0, ha0l = (short8)0, ha1l = (short8)0;
  if (HAS_H) {
    __syncthreads();
    stage_tile(aggH, blk * 64, th, tl, t);
    __syncthreads();
    ha0h = *(const short8*)(th + abase);
    ha1h = *(const short8*)(th + abase + 32);
    ha0l = *(const short8*)(tl + abase);
    ha1l = *(const short8*)(tl + abase + 32);
  }

  float gfhw[4], gfxw[4], guhw[4], guxw[4];
#pragma unroll
  for (int tc = 0; tc < 4; ++tc) {
    gfhw[tc] = gfw[lr + 16 * tc]; gfxw[tc] = gfw[64 + lr + 16 * tc];
    guhw[tc] = guw[lr + 16 * tc]; guxw[tc] = guw[64 + lr + 16 * tc];
  }
  const float gfb0 = gfb[0], gub0 = gub[0];

  float acc[4][4];
#pragma unroll
  for (int tc = 0; tc < 4; ++tc)
#pragma unroll
    for (int r = 0; r < 4; ++r) acc[tc][r] = 0.f;

  for (int k = 0; k < 4; ++k) {
    f32x4 cx[4], ch[4];
#pragma unroll
    for (int tc = 0; tc < 4; ++tc) { cx[tc] = (f32x4)0.f; ch[tc] = (f32x4)0.f; }
    __syncthreads();  // prior bsta readers done
    stageB(wxp + k * 8192, bsta, t);
    __syncthreads();
    mm_mfma_l<4>(xa0h, xa1h, xa0l, xa1l, bsta, l, cx);
    if (HAS_H) {
      __syncthreads();
      stageB(whp + k * 8192, bsta, t);
      __syncthreads();
      mm_mfma_l<4>(ha0h, ha1h, ha0l, ha1l, bsta, l, ch);
    }

    float Cx[4][4], Ch[4][4];
#pragma unroll
    for (int tc = 0; tc < 4; ++tc) {
      float bxv = bxl[k * 64 + lr + 16 * tc];
      float bhv = bhl[k * 64 + lr + 16 * tc];
#pragma unroll
      for (int r = 0; r < 4; ++r) {
        Cx[tc][r] = cx[tc][r] + bxv;
        Ch[tc][r] = (HAS_H ? ch[tc][r] : 0.f) + bhv;
      }
    }
#pragma unroll
    for (int r = 0; r < 4; ++r) {
      float pf = 0.f, pu = 0.f;
#pragma unroll
      for (int tc = 0; tc < 4; ++tc) {
        pf = fmaf(Ch[tc][r], gfhw[tc], pf); pf = fmaf(Cx[tc][r], gfxw[tc], pf);
        pu = fmaf(Ch[tc][r], guhw[tc], pu); pu = fmaf(Cx[tc][r], guxw[tc], pu);
      }
      pf = red16(pf); pu = red16(pu);
      float fv = ALPHA_C * ftanh(pf + gfb0);
      float uv = ALPHA_C * ftanh(pu + gub0);
#pragma unroll
      for (int tc = 0; tc < 4; ++tc)
        acc[tc][r] += (1.f + fv) * Ch[tc][r] + (1.f + uv) * Cx[tc][r];
    }
  }

  // hmid = acc/4 + h_in ; LN
  float hmid[4][4];
#pragma unroll
  for (int tc = 0; tc < 4; ++tc)
#pragma unroll
    for (int r = 0; r < 4; ++r) {
      float hv = 0.f;
      if (HAS_H) {
        int gn = blk * 64 + 16 * w + 4 * lg + r;
        if (gn > NN - 1) gn = NN - 1;
        hv = h_in[gn * 64 + lr + 16 * tc];
      }
      hmid[tc][r] = fmaf(acc[tc][r], 0.25f, hv);
    }
  ln_frag(hmid);

  __syncthreads();  // A-frag LDS reads long done; safe to reuse tile
#pragma unroll
  for (int tc = 0; tc < 4; ++tc)
#pragma unroll
    for (int r = 0; r < 4; ++r) {
      int o = (16 * w + 4 * lg + r) * PITCH + lr + 16 * tc;
      ushort h = f2bf(hmid[tc][r]);
      th[o] = h;
      tl[o] = f2bf(hmid[tc][r] - bf2f(h));
    }
  __syncthreads();
  short8 m0h = *(const short8*)(th + abase);
  short8 m1h = *(const short8*)(th + abase + 32);
  short8 m0l = *(const short8*)(tl + abase);
  short8 m1l = *(const short8*)(tl + abase + 32);

  f32x4 f1[4];
#pragma unroll
  for (int tc = 0; tc < 4; ++tc) f1[tc] = (f32x4)0.f;
  __syncthreads();  // prior bsta readers + m-frag reads done
  stageB(ff1p, bsta, t);
  __syncthreads();
  mm_mfma_l<4>(m0h, m1h, m0l, m1l, bsta, l, f1);
#pragma unroll
  for (int tc = 0; tc < 4; ++tc) {
    float bv = ff1b[lr + 16 * tc];
#pragma unroll
    for (int r = 0; r < 4; ++r) {
      float v = fmaxf(f1[tc][r] + bv, 0.f);
      int o = (16 * w + 4 * lg + r) * PITCH + lr + 16 * tc;
      ushort h = f2bf(v);
      th[o] = h;
      tl[o] = f2bf(v - bf2f(h));
    }
  }
  __syncthreads();
  short8 g0h = *(const short8*)(th + abase);
  short8 g1h = *(const short8*)(th + abase + 32);
  short8 g0l = *(const short8*)(tl + abase);
  short8 g1l = *(const short8*)(tl + abase + 32);

  f32x4 f2[4];
#pragma unroll
  for (int tc = 0; tc < 4; ++tc) f2[tc] = (f32x4)0.f;
  __syncthreads();
  stageB(ff2p, bsta, t);
  __syncthreads();
  mm_mfma_l<4>(g0h, g1h, g0l, g1l, bsta, l, f2);
  float F2[4][4];
#pragma unroll
  for (int tc = 0; tc < 4; ++tc) {
    float bv = ff2b[lr + 16 * tc];
#pragma unroll
    for (int r = 0; r < 4; ++r) F2[tc][r] = f2[tc][r] + bv + hmid[tc][r];
  }
  ln_frag(F2);

  if (!DO_CLF) {
#pragma unroll
    for (int r = 0; r < 4; ++r) {
      int gn = blk * 64 + 16 * w + 4 * lg + r;
      if (gn < NN) {
        float dv = WSC ? dinv[gn] : 0.f;
#pragma unroll
        for (int tc = 0; tc < 4; ++tc) {
          h_out[gn * 64 + lr + 16 * tc] = F2[tc][r];
          if (WSC) hs_out[gn * 64 + lr + 16 * tc] = F2[tc][r] * dv;
        }
      }
    }
    return;
  }

  // ===== classifier tail (DO_CLF): relu(F2@c1+b1)@c2+b2 -> outv =====
  __syncthreads();  // all waves past FF2 mm (bsta + tile reads retired)
#pragma unroll
  for (int tc = 0; tc < 4; ++tc)
#pragma unroll
    for (int r = 0; r < 4; ++r) {
      int o = (16 * w + 4 * lg + r) * PITCH + lr + 16 * tc;
      ushort h = f2bf(F2[tc][r]);
      th[o] = h;
      tl[o] = f2bf(F2[tc][r] - bf2f(h));
    }
  stageB(c1p, bsta, t);
  __syncthreads();
  short8 p0h = *(const short8*)(th + abase);
  short8 p1h = *(const short8*)(th + abase + 32);
  short8 p0l = *(const short8*)(tl + abase);
  short8 p1l = *(const short8*)(tl + abase + 32);

  f32x4 c1[4];
#pragma unroll
  for (int tc = 0; tc < 4; ++tc) c1[tc] = (f32x4)0.f;
  mm_mfma_l<4>(p0h, p1h, p0l, p1l, bsta, l, c1);
  __syncthreads();  // bsta + tile reads retired before overwrite
#pragma unroll
  for (int tc = 0; tc < 4; ++tc) {
    float bv = c1b[lr + 16 * tc];
#pragma unroll
    for (int r = 0; r < 4; ++r) {
      float v = fmaxf(c1[tc][r] + bv, 0.f);
      int o = (16 * w + 4 * lg + r) * PITCH + lr + 16 * tc;
      ushort hh = f2bf(v);
      th[o] = hh;
      tl[o] = f2bf(v - bf2f(hh));
    }
  }
  stageB(c2p, bsta, t);
  __syncthreads();
  short8 q0h = *(const short8*)(th + abase);
  short8 q1h = *(const short8*)(th + abase + 32);
  short8 q0l = *(const short8*)(tl + abase);
  short8 q1l = *(const short8*)(tl + abase + 32);

  f32x4 c2[3];
#pragma unroll
  for (int tc = 0; tc < 3; ++tc) c2[tc] = (f32x4)0.f;
  mm_mfma_l<3>(q0h, q1h, q0l, q1l, bsta, l, c2);
#pragma unroll
  for (int tc = 0; tc < 3; ++tc) {
    int cc = lr + 16 * tc;
    if (cc < 40) {
      float bv = c2b[cc];
#pragma unroll
      for (int r = 0; r < 4; ++r) {
        int gn = blk * 64 + 16 * w + 4 * lg + r;
        if (gn < NN) outv[gn * 40 + cc] = c2[tc][r] + bv;
      }
    }
  }
}

// ---------------- launch ----------------

extern "C" void kernel_launch(void* const* d_in, const int* in_sizes, int n_in,
                              void* d_out, int out_size, void* d_ws, size_t ws_size,
                              hipStream_t stream) {
  (void)in_sizes; (void)n_in; (void)out_size; (void)ws_size;
  const float* x    = (const float*)d_in[0];
  const int*   ei   = (const int*)d_in[1];
  const float* Wh   = (const float*)d_in[2];
  const float* bh   = (const float*)d_in[3];
  const float* Wx   = (const float*)d_in[4];
  const float* bx   = (const float*)d_in[5];
  const float* gfw  = (const float*)d_in[6];
  const float* gfb  = (const float*)d_in[7];
  const float* guw  = (const float*)d_in[8];
  const float* gub  = (const float*)d_in[9];
  const float* ff1w = (const float*)d_in[10];
  const float* ff1b = (const float*)d_in[11];
  const float* ff2w = (const float*)d_in[12];
  const float* ff2b = (const float*)d_in[13];
  const float* c1w  = (const float*)d_in[14];
  const float* c1b  = (const float*)d_in[15];
  const float* c2w  = (const float*)d_in[16];
  const float* c2b  = (const float*)d_in[17];
  float* outv = (float*)d_out;

  char* ws = (char*)d_ws;
  size_t o = 0;
  auto take = [&](size_t b) { char* p = ws + o; o += (b + 255) & ~(size_t)255; return p; };
  int*    deg  = (int*)take((size_t)NN * 4);
  int*    fill = (int*)take((size_t)NN * 4);
  int*    rowp = (int*)take((size_t)(NN + 1) * 4);
  int*    bsum = (int*)take(512 * 4);
  int*    col  = (int*)take((size_t)EE * 4);
  float*  dinv = (float*)take((size_t)NN * 4);
  ushort* wpk  = (ushort*)take((size_t)22 * 8192 * 2);
  float*  aggX = (float*)take((size_t)NN * 64 * 4);
  float*  aggH = (float*)take((size_t)NN * 64 * 4);
  float*  hbuf = (float*)take((size_t)NN * 64 * 4);
  float*  xsc  = (float*)take((size_t)NN * 64 * 4);

  const int* srcv = ei;
  const int* dstv = ei + EE;

  const int NB_E = (EE + 255) / 256;
  const int NB_N = (NN + 255) / 256;   // 391 >= 22 pack blocks
  const int NB_V4 = (NN * 16 + 255) / 256;

  k_packz<<<NB_N, 256, 0, stream>>>(Wh, Wx, ff1w, ff2w, c1w, c2w, wpk, deg, fill);
  k_count<<<NB_E, 256, 0, stream>>>(dstv, deg);
  k_scan1<<<NB_N, 256, 0, stream>>>(deg, rowp, bsum, dinv);
  k_scan2<<<1, 512, 0, stream>>>(bsum, rowp, NB_N);
  k_scan3<<<NB_N, 256, 0, stream>>>(rowp, bsum);
  k_fill<<<NB_E, 256, 0, stream>>>(srcv, dstv, rowp, fill, col);

  // AggX
  k_prescale<<<NB_V4, 256, 0, stream>>>(x, dinv, xsc);
  k_spmm<<<(NN + 15) / 16, 256, 0, stream>>>((const float4*)xsc, dinv, rowp, col, (float4*)aggX);

  const int NB_L = (NN + 63) / 64;
  // layer 0 (h=0); writes h1 (hbuf) and h1*dinv (xsc)
  k_layer<0, 1, 0><<<NB_L, 256, 0, stream>>>(
      aggX, aggX, hbuf, hbuf, xsc, dinv,
      wpk + 0 * 8192, wpk + 8 * 8192, bx, bh, gfw, gfb, guw, gub,
      wpk + 16 * 8192, ff1b, wpk + 18 * 8192, ff2b,
      wpk + 20 * 8192, c1b, wpk + 21 * 8192, c2b, outv);

  // AggH
  k_spmm<<<(NN + 15) / 16, 256, 0, stream>>>((const float4*)xsc, dinv, rowp, col, (float4*)aggH);

  // layer 1 + fused classifier -> outv
  k_layer<1, 0, 1><<<NB_L, 256, 0, stream>>>(
      aggX, aggH, hbuf, hbuf, xsc, dinv,
      wpk + 4 * 8192, wpk + 12 * 8192, bx + 256, bh + 256, gfw, gfb, guw, gub,
      wpk + 17 * 8192, ff1b + 64, wpk + 19 * 8192, ff2b + 64,
      wpk + 20 * 8192, c1b, wpk + 21 * 8192, c2b, outv);
}

// Round 12
// 338.028 us; speedup vs baseline: 1.1777x; 1.1267x over previous
//
#include <hip/hip_runtime.h>

#define NN 100000
#define EE 1200000
#define ALPHA_C 0.2f
#define EPS_C 1e-5f

typedef __attribute__((ext_vector_type(8))) short short8;
typedef __attribute__((ext_vector_type(4))) float f32x4;
#define MFMA __builtin_amdgcn_mfma_f32_16x16x32_bf16

#define PITCH 72  // LDS tile pitch (ushorts): 144B rows, 16B-aligned frags

// ---------------- bf16 helpers ----------------

__device__ __forceinline__ ushort f2bf(float f) {
  unsigned u = __float_as_uint(f);
  unsigned r = (u + 0x7FFFu + ((u >> 16) & 1u)) >> 16;
  return (ushort)r;
}
__device__ __forceinline__ float bf2f(ushort h) { return __uint_as_float((unsigned)h << 16); }

__device__ __forceinline__ float ftanh(float x) {  // validated (round 8/11 pass)
  float ax = fabsf(x);
  float e = __expf(2.f * ax);
  float t = 1.f - 2.f / (e + 1.f);
  return copysignf(t, x);
}

// ---------------- CSR build ----------------

// count + per-edge rank (position within its dst row)
__global__ __launch_bounds__(256) void k_countrank(const int* __restrict__ dstv,
                                                   int* __restrict__ deg, int* __restrict__ rank) {
  int e = blockIdx.x * 256 + threadIdx.x;
  if (e < EE) rank[e] = atomicAdd(&deg[dstv[e]], 1);
}

__global__ __launch_bounds__(256) void k_scan1(const int* __restrict__ deg, int* __restrict__ rowp,
                                               int* __restrict__ bsum, float* __restrict__ dinv) {
  __shared__ int s[256];
  int t = threadIdx.x;
  int i = blockIdx.x * 256 + t;
  int v = (i < NN) ? deg[i] : 0;
  if (i < NN) dinv[i] = rsqrtf((float)v + 1.0f);  // +1 self-loop
  s[t] = v;
  __syncthreads();
  for (int off = 1; off < 256; off <<= 1) {
    int add = (t >= off) ? s[t - off] : 0;
    __syncthreads();
    s[t] += add;
    __syncthreads();
  }
  if (i < NN) rowp[i] = s[t] - v;
  if (t == 255) bsum[blockIdx.x] = s[255];
}

__global__ __launch_bounds__(512) void k_scan2(int* __restrict__ bsum, int* __restrict__ rowp, int nb) {
  __shared__ int s[512];
  int t = threadIdx.x;
  int v = (t < nb) ? bsum[t] : 0;
  s[t] = v;
  __syncthreads();
  for (int off = 1; off < 512; off <<= 1) {
    int add = (t >= off) ? s[t - off] : 0;
    __syncthreads();
    s[t] += add;
    __syncthreads();
  }
  if (t < nb) bsum[t] = s[t] - v;
  if (t == 0) rowp[NN] = EE;
}

__global__ __launch_bounds__(256) void k_scan3(int* __restrict__ rowp, const int* __restrict__ bsum) {
  int i = blockIdx.x * 256 + threadIdx.x;
  if (i < NN) rowp[i] += bsum[blockIdx.x];
}

// atomic-free fill using precomputed rank
__global__ __launch_bounds__(256) void k_fill(const int* __restrict__ srcv, const int* __restrict__ dstv,
                                              const int* __restrict__ rowp, const int* __restrict__ rank,
                                              int* __restrict__ col) {
  int e = blockIdx.x * 256 + threadIdx.x;
  if (e < EE) col[rowp[dstv[e]] + rank[e]] = srcv[e];
}

// ---------------- SpMM ----------------

__global__ __launch_bounds__(256) void k_prescale(const float* __restrict__ feat,
                                                  const float* __restrict__ dinv,
                                                  float* __restrict__ xs) {
  int idx = blockIdx.x * 256 + threadIdx.x;
  if (idx < NN * 16) {
    float4 v = ((const float4*)feat)[idx];
    float d = dinv[idx >> 4];
    v.x *= d; v.y *= d; v.z *= d; v.w *= d;
    ((float4*)xs)[idx] = v;
  }
}

// out: packed bf16 hi||lo A-fragment layout, 128 ushorts/node ([64 hi][64 lo])
__global__ __launch_bounds__(256) void k_spmm(const float4* __restrict__ xs4, const float* __restrict__ dinv,
                                              const int* __restrict__ rowp, const int* __restrict__ col,
                                              ushort* __restrict__ outP) {
  int node = blockIdx.x * 16 + (threadIdx.x >> 4);
  int q = threadIdx.x & 15;
  if (node >= NN) return;
  int s = rowp[node], e = rowp[node + 1];
  float4 a0 = {0.f, 0.f, 0.f, 0.f}, a1 = a0, a2 = a0, a3 = a0;
  int j = s;
  for (; j + 4 <= e; j += 4) {
    int c0 = col[j], c1 = col[j + 1], c2 = col[j + 2], c3 = col[j + 3];
    float4 v0 = xs4[c0 * 16 + q];
    float4 v1 = xs4[c1 * 16 + q];
    float4 v2 = xs4[c2 * 16 + q];
    float4 v3 = xs4[c3 * 16 + q];
    a0 += v0; a1 += v1; a2 += v2; a3 += v3;
  }
  for (; j < e; ++j) a0 += xs4[col[j] * 16 + q];
  float4 sv = xs4[node * 16 + q];
  float d = dinv[node];
  float4 o;
  o.x = d * (a0.x + a1.x + a2.x + a3.x + sv.x);
  o.y = d * (a0.y + a1.y + a2.y + a3.y + sv.y);
  o.z = d * (a0.z + a1.z + a2.z + a3.z + sv.z);
  o.w = d * (a0.w + a1.w + a2.w + a3.w + sv.w);
  ushort h0 = f2bf(o.x), h1 = f2bf(o.y), h2 = f2bf(o.z), h3 = f2bf(o.w);
  ushort l0 = f2bf(o.x - bf2f(h0)), l1 = f2bf(o.y - bf2f(h1)),
         l2 = f2bf(o.z - bf2f(h2)), l3 = f2bf(o.w - bf2f(h3));
  ushort* p = outP + (size_t)node * 128 + 4 * q;
  *(ushort4*)(p) = make_ushort4(h0, h1, h2, h3);
  *(ushort4*)(p + 64) = make_ushort4(l0, l1, l2, l3);
}

// ---------------- weight pre-pack (B-fragment order, hi||lo bf16) + deg zero ----------
// frag f = tc*2+kh; lane l, j: value = W[32*kh + 8*(l>>4) + j][16*tc + (l&15)]
// ids: 0..7 Wx(l*4+k), 8..15 Wh, 16..17 ff1, 18..19 ff2, 20 clf1, 21 clf2(64x40 pad)

__global__ __launch_bounds__(256) void k_packz(const float* __restrict__ Wh, const float* __restrict__ Wx,
                                               const float* __restrict__ ff1w, const float* __restrict__ ff2w,
                                               const float* __restrict__ c1w, const float* __restrict__ c2w,
                                               ushort* __restrict__ wpk, int* __restrict__ deg) {
  int i = blockIdx.x * 256 + threadIdx.x;
  if (i < NN) deg[i] = 0;
  int id = blockIdx.x;
  if (id >= 22) return;
  const float* src;
  int ncol = 64, vcol = 64;
  if (id < 8) src = Wx + id * 4096;
  else if (id < 16) src = Wh + (id - 8) * 4096;
  else if (id < 18) src = ff1w + (id - 16) * 4096;
  else if (id < 20) src = ff2w + (id - 18) * 4096;
  else if (id == 20) src = c1w;
  else { src = c2w; ncol = 40; vcol = 40; }
  ushort* dst = wpk + (size_t)id * 8192;
  for (int p = threadIdx.x; p < 512; p += 256) {
    int f = p >> 6, l = p & 63;
    int kh = f & 1, tc = f >> 1;
    int r0 = 32 * kh + 8 * (l >> 4), c = 16 * tc + (l & 15);
#pragma unroll
    for (int j = 0; j < 8; ++j) {
      float v = (c < vcol) ? src[(r0 + j) * ncol + c] : 0.f;
      ushort h = f2bf(v);
      dst[f * 512 + l * 8 + j] = h;
      dst[4096 + f * 512 + l * 8 + j] = f2bf(v - bf2f(h));
    }
  }
}

// ---------------- dense helpers ----------------

__device__ __forceinline__ float red16(float v) {
  v += __shfl_xor(v, 1);
  v += __shfl_xor(v, 2);
  v += __shfl_xor(v, 4);
  v += __shfl_xor(v, 8);
  return v;
}

// cooperative sync copy of one packed matmul (8192 ushort = 16KB) global -> LDS
__device__ __forceinline__ void stageB(const ushort* __restrict__ wp, ushort* __restrict__ bsta, int t) {
#pragma unroll
  for (int u = 0; u < 4; ++u) {
    int o = (u * 256 + t) * 8;
    *(short8*)(bsta + o) = *(const short8*)(wp + o);
  }
}

// split-precision MFMA: A-frags in regs, B-frags from LDS (staged packed matmul)
template <int NT>
__device__ __forceinline__ void mm_mfma_l(short8 a0h, short8 a1h, short8 a0l, short8 a1l,
                                          const ushort* __restrict__ bsta, int l, f32x4* C) {
#pragma unroll
  for (int tc = 0; tc < NT; ++tc) {
#pragma unroll
    for (int kh = 0; kh < 2; ++kh) {
      const short8 bh = *(const short8*)(bsta + (tc * 2 + kh) * 512 + l * 8);
      const short8 bl = *(const short8*)(bsta + 4096 + (tc * 2 + kh) * 512 + l * 8);
      const short8 ah = kh ? a1h : a0h;
      const short8 alo = kh ? a1l : a0l;
      C[tc] = MFMA(ah, bh, C[tc], 0, 0, 0);
      C[tc] = MFMA(ah, bl, C[tc], 0, 0, 0);
      C[tc] = MFMA(alo, bh, C[tc], 0, 0, 0);
    }
  }
}

__device__ __forceinline__ void ln_frag(float v[4][4]) {
#pragma unroll
  for (int r = 0; r < 4; ++r) {
    float s = v[0][r] + v[1][r] + v[2][r] + v[3][r];
    s = red16(s);
    float mu = s * 0.015625f;
    float q = 0.f;
#pragma unroll
    for (int tc = 0; tc < 4; ++tc) { float d = v[tc][r] - mu; q = fmaf(d, d, q); }
    q = red16(q);
    float inv = rsqrtf(q * 0.015625f + EPS_C);
#pragma unroll
    for (int tc = 0; tc < 4; ++tc) v[tc][r] = (v[tc][r] - mu) * inv;
  }
}

// ---------------- fused per-layer kernel ----------------
// 64 nodes/block, 4 waves; wave w rows 16w..16w+15. A-frags direct from packed global
// (spmm output, hi||lo layout) — no A staging. B via sync LDS stage (proven round-5/11
// structure). DO_CLF=1 appends classifier, writes outv.
// C/D frag: row = 16w + 4*(l>>4) + r, col = (l&15) + 16*tc.

template <int HAS_H, int WSC, int DO_CLF>
__global__ __launch_bounds__(256) void k_layer(
    const ushort* __restrict__ aggXP, const ushort* __restrict__ aggHP,
    const float* __restrict__ h_in, float* __restrict__ h_out,
    float* __restrict__ hs_out, const float* __restrict__ dinv,
    const ushort* __restrict__ wxp, const ushort* __restrict__ whp,
    const float* __restrict__ bxl, const float* __restrict__ bhl,
    const float* __restrict__ gfw, const float* __restrict__ gfb,
    const float* __restrict__ guw, const float* __restrict__ gub,
    const ushort* __restrict__ ff1p, const float* __restrict__ ff1b,
    const ushort* __restrict__ ff2p, const float* __restrict__ ff2b,
    const ushort* __restrict__ c1p, const float* __restrict__ c1b,
    const ushort* __restrict__ c2p, const float* __restrict__ c2b,
    float* __restrict__ outv) {
  __shared__ __align__(16) ushort th[64 * PITCH], tl[64 * PITCH];
  __shared__ __align__(16) ushort bsta[8192];
  const int t = threadIdx.x, blk = blockIdx.x;
  const int w = t >> 6, l = t & 63, lg = l >> 4, lr = l & 15;
  const int abase = (16 * w + lr) * PITCH + 8 * lg;
  const int arow = blk * 64 + 16 * w + lr;  // < NN+? blk*64+63 <= 99967+... NN%64==0? 100000/64=1562.5 -> last block partial
  const int arowc = arow < NN ? arow : NN - 1;

  // A-fragments direct from packed agg (hi at +0, lo at +64; k-halves at +0/+32)
  const ushort* axp = aggXP + (size_t)arowc * 128 + 8 * lg;
  short8 xa0h = *(const short8*)(axp);
  short8 xa1h = *(const short8*)(axp + 32);
  short8 xa0l = *(const short8*)(axp + 64);
  short8 xa1l = *(const short8*)(axp + 96);
  short8 ha0h = (short8)0, ha1h = (short8)0, ha0l = (short8)0, ha1l = (short8)0;
  if (HAS_H) {
    const ushort* ahp = aggHP + (size_t)arowc * 128 + 8 * lg;
    ha0h = *(const short8*)(ahp);
    ha1h = *(const short8*)(ahp + 32);
    ha0l = *(const short8*)(ahp + 64);
    ha1l = *(const short8*)(ahp + 96);
  }

  float gfhw[4], gfxw[4], guhw[4], guxw[4];
#pragma unroll
  for (int tc = 0; tc < 4; ++tc) {
    gfhw[tc] = gfw[lr + 16 * tc]; gfxw[tc] = gfw[64 + lr + 16 * tc];
    guhw[tc] = guw[lr + 16 * tc]; guxw[tc] = guw[64 + lr + 16 * tc];
  }
  const float gfb0 = gfb[0], gub0 = gub[0];

  float acc[4][4];
#pragma unroll
  for (int tc = 0; tc < 4; ++tc)
#pragma unroll
    for (int r = 0; r < 4; ++r) acc[tc][r] = 0.f;

  for (int k = 0; k < 4; ++k) {
    f32x4 cx[4], ch[4];
#pragma unroll
    for (int tc = 0; tc < 4; ++tc) { cx[tc] = (f32x4)0.f; ch[tc] = (f32x4)0.f; }
    __syncthreads();  // prior bsta readers done
    stageB(wxp + k * 8192, bsta, t);
    __syncthreads();
    mm_mfma_l<4>(xa0h, xa1h, xa0l, xa1l, bsta, l, cx);
    if (HAS_H) {
      __syncthreads();
      stageB(whp + k * 8192, bsta, t);
      __syncthreads();
      mm_mfma_l<4>(ha0h, ha1h, ha0l, ha1l, bsta, l, ch);
    }

    float Cx[4][4], Ch[4][4];
#pragma unroll
    for (int tc = 0; tc < 4; ++tc) {
      float bxv = bxl[k * 64 + lr + 16 * tc];
      float bhv = bhl[k * 64 + lr + 16 * tc];
#pragma unroll
      for (int r = 0; r < 4; ++r) {
        Cx[tc][r] = cx[tc][r] + bxv;
        Ch[tc][r] = (HAS_H ? ch[tc][r] : 0.f) + bhv;
      }
    }
#pragma unroll
    for (int r = 0; r < 4; ++r) {
      float pf = 0.f, pu = 0.f;
#pragma unroll
      for (int tc = 0; tc < 4; ++tc) {
        pf = fmaf(Ch[tc][r], gfhw[tc], pf); pf = fmaf(Cx[tc][r], gfxw[tc], pf);
        pu = fmaf(Ch[tc][r], guhw[tc], pu); pu = fmaf(Cx[tc][r], guxw[tc], pu);
      }
      pf = red16(pf); pu = red16(pu);
      float fv = ALPHA_C * ftanh(pf + gfb0);
      float uv = ALPHA_C * ftanh(pu + gub0);
#pragma unroll
      for (int tc = 0; tc < 4; ++tc)
        acc[tc][r] += (1.f + fv) * Ch[tc][r] + (1.f + uv) * Cx[tc][r];
    }
  }

  // hmid = acc/4 + h_in ; LN
  float hmid[4][4];
#pragma unroll
  for (int tc = 0; tc < 4; ++tc)
#pragma unroll
    for (int r = 0; r < 4; ++r) {
      float hv = 0.f;
      if (HAS_H) {
        int gn = blk * 64 + 16 * w + 4 * lg + r;
        if (gn > NN - 1) gn = NN - 1;
        hv = h_in[gn * 64 + lr + 16 * tc];
      }
      hmid[tc][r] = fmaf(acc[tc][r], 0.25f, hv);
    }
  ln_frag(hmid);

  __syncthreads();  // all waves past last head phase (bsta reads retired)
#pragma unroll
  for (int tc = 0; tc < 4; ++tc)
#pragma unroll
    for (int r = 0; r < 4; ++r) {
      int o = (16 * w + 4 * lg + r) * PITCH + lr + 16 * tc;
      ushort h = f2bf(hmid[tc][r]);
      th[o] = h;
      tl[o] = f2bf(hmid[tc][r] - bf2f(h));
    }
  __syncthreads();
  short8 m0h = *(const short8*)(th + abase);
  short8 m1h = *(const short8*)(th + abase + 32);
  short8 m0l = *(const short8*)(tl + abase);
  short8 m1l = *(const short8*)(tl + abase + 32);

  f32x4 f1[4];
#pragma unroll
  for (int tc = 0; tc < 4; ++tc) f1[tc] = (f32x4)0.f;
  __syncthreads();  // m-frag reads done (held in regs) before bsta restage
  stageB(ff1p, bsta, t);
  __syncthreads();
  mm_mfma_l<4>(m0h, m1h, m0l, m1l, bsta, l, f1);
#pragma unroll
  for (int tc = 0; tc < 4; ++tc) {
    float bv = ff1b[lr + 16 * tc];
#pragma unroll
    for (int r = 0; r < 4; ++r) {
      float v = fmaxf(f1[tc][r] + bv, 0.f);
      int o = (16 * w + 4 * lg + r) * PITCH + lr + 16 * tc;
      ushort h = f2bf(v);
      th[o] = h;
      tl[o] = f2bf(v - bf2f(h));
    }
  }
  __syncthreads();
  short8 g0h = *(const short8*)(th + abase);
  short8 g1h = *(const short8*)(th + abase + 32);
  short8 g0l = *(const short8*)(tl + abase);
  short8 g1l = *(const short8*)(tl + abase + 32);

  f32x4 f2[4];
#pragma unroll
  for (int tc = 0; tc < 4; ++tc) f2[tc] = (f32x4)0.f;
  __syncthreads();
  stageB(ff2p, bsta, t);
  __syncthreads();
  mm_mfma_l<4>(g0h, g1h, g0l, g1l, bsta, l, f2);
  float F2[4][4];
#pragma unroll
  for (int tc = 0; tc < 4; ++tc) {
    float bv = ff2b[lr + 16 * tc];
#pragma unroll
    for (int r = 0; r < 4; ++r) F2[tc][r] = f2[tc][r] + bv + hmid[tc][r];
  }
  ln_frag(F2);

  if (!DO_CLF) {
#pragma unroll
    for (int r = 0; r < 4; ++r) {
      int gn = blk * 64 + 16 * w + 4 * lg + r;
      if (gn < NN) {
        float dv = WSC ? dinv[gn] : 0.f;
#pragma unroll
        for (int tc = 0; tc < 4; ++tc) {
          h_out[gn * 64 + lr + 16 * tc] = F2[tc][r];
          if (WSC) hs_out[gn * 64 + lr + 16 * tc] = F2[tc][r] * dv;
        }
      }
    }
    return;
  }

  // ===== classifier tail (DO_CLF): relu(F2@c1+b1)@c2+b2 -> outv =====
  __syncthreads();  // all waves past FF2 mm (bsta + tile reads retired)
#pragma unroll
  for (int tc = 0; tc < 4; ++tc)
#pragma unroll
    for (int r = 0; r < 4; ++r) {
      int o = (16 * w + 4 * lg + r) * PITCH + lr + 16 * tc;
      ushort h = f2bf(F2[tc][r]);
      th[o] = h;
      tl[o] = f2bf(F2[tc][r] - bf2f(h));
    }
  stageB(c1p, bsta, t);
  __syncthreads();
  short8 p0h = *(const short8*)(th + abase);
  short8 p1h = *(const short8*)(th + abase + 32);
  short8 p0l = *(const short8*)(tl + abase);
  short8 p1l = *(const short8*)(tl + abase + 32);

  f32x4 c1[4];
#pragma unroll
  for (int tc = 0; tc < 4; ++tc) c1[tc] = (f32x4)0.f;
  mm_mfma_l<4>(p0h, p1h, p0l, p1l, bsta, l, c1);
  __syncthreads();  // bsta + tile reads retired before overwrite
#pragma unroll
  for (int tc = 0; tc < 4; ++tc) {
    float bv = c1b[lr + 16 * tc];
#pragma unroll
    for (int r = 0; r < 4; ++r) {
      float v = fmaxf(c1[tc][r] + bv, 0.f);
      int o = (16 * w + 4 * lg + r) * PITCH + lr + 16 * tc;
      ushort hh = f2bf(v);
      th[o] = hh;
      tl[o] = f2bf(v - bf2f(hh));
    }
  }
  stageB(c2p, bsta, t);
  __syncthreads();
  short8 q0h = *(const short8*)(th + abase);
  short8 q1h = *(const short8*)(th + abase + 32);
  short8 q0l = *(const short8*)(tl + abase);
  short8 q1l = *(const short8*)(tl + abase + 32);

  f32x4 c2[3];
#pragma unroll
  for (int tc = 0; tc < 3; ++tc) c2[tc] = (f32x4)0.f;
  mm_mfma_l<3>(q0h, q1h, q0l, q1l, bsta, l, c2);
#pragma unroll
  for (int tc = 0; tc < 3; ++tc) {
    int cc = lr + 16 * tc;
    if (cc < 40) {
      float bv = c2b[cc];
#pragma unroll
      for (int r = 0; r < 4; ++r) {
        int gn = blk * 64 + 16 * w + 4 * lg + r;
        if (gn < NN) outv[gn * 40 + cc] = c2[tc][r] + bv;
      }
    }
  }
}

// ---------------- launch ----------------

extern "C" void kernel_launch(void* const* d_in, const int* in_sizes, int n_in,
                              void* d_out, int out_size, void* d_ws, size_t ws_size,
                              hipStream_t stream) {
  (void)in_sizes; (void)n_in; (void)out_size; (void)ws_size;
  const float* x    = (const float*)d_in[0];
  const int*   ei   = (const int*)d_in[1];
  const float* Wh   = (const float*)d_in[2];
  const float* bh   = (const float*)d_in[3];
  const float* Wx   = (const float*)d_in[4];
  const float* bx   = (const float*)d_in[5];
  const float* gfw  = (const float*)d_in[6];
  const float* gfb  = (const float*)d_in[7];
  const float* guw  = (const float*)d_in[8];
  const float* gub  = (const float*)d_in[9];
  const float* ff1w = (const float*)d_in[10];
  const float* ff1b = (const float*)d_in[11];
  const float* ff2w = (const float*)d_in[12];
  const float* ff2b = (const float*)d_in[13];
  const float* c1w  = (const float*)d_in[14];
  const float* c1b  = (const float*)d_in[15];
  const float* c2w  = (const float*)d_in[16];
  const float* c2b  = (const float*)d_in[17];
  float* outv = (float*)d_out;

  char* ws = (char*)d_ws;
  size_t o = 0;
  auto take = [&](size_t b) { char* p = ws + o; o += (b + 255) & ~(size_t)255; return p; };
  int*    deg  = (int*)take((size_t)NN * 4);
  int*    rank = (int*)take((size_t)EE * 4);
  int*    rowp = (int*)take((size_t)(NN + 1) * 4);
  int*    bsum = (int*)take(512 * 4);
  int*    col  = (int*)take((size_t)EE * 4);
  float*  dinv = (float*)take((size_t)NN * 4);
  ushort* wpk  = (ushort*)take((size_t)22 * 8192 * 2);
  ushort* aggXP = (ushort*)take((size_t)NN * 128 * 2);
  ushort* aggHP = (ushort*)take((size_t)NN * 128 * 2);
  float*  hbuf = (float*)take((size_t)NN * 64 * 4);
  float*  xsc  = (float*)take((size_t)NN * 64 * 4);

  const int* srcv = ei;
  const int* dstv = ei + EE;

  const int NB_E = (EE + 255) / 256;
  const int NB_N = (NN + 255) / 256;   // 391 >= 22 pack blocks
  const int NB_V4 = (NN * 16 + 255) / 256;

  k_packz<<<NB_N, 256, 0, stream>>>(Wh, Wx, ff1w, ff2w, c1w, c2w, wpk, deg);
  k_countrank<<<NB_E, 256, 0, stream>>>(dstv, deg, rank);
  k_scan1<<<NB_N, 256, 0, stream>>>(deg, rowp, bsum, dinv);
  k_scan2<<<1, 512, 0, stream>>>(bsum, rowp, NB_N);
  k_scan3<<<NB_N, 256, 0, stream>>>(rowp, bsum);
  k_fill<<<NB_E, 256, 0, stream>>>(srcv, dstv, rowp, rank, col);

  // AggX (packed bf16 hi/lo)
  k_prescale<<<NB_V4, 256, 0, stream>>>(x, dinv, xsc);
  k_spmm<<<(NN + 15) / 16, 256, 0, stream>>>((const float4*)xsc, dinv, rowp, col, aggXP);

  const int NB_L = (NN + 63) / 64;
  // layer 0 (h=0); writes h1 (hbuf) and h1*dinv (xsc)
  k_layer<0, 1, 0><<<NB_L, 256, 0, stream>>>(
      aggXP, aggXP, hbuf, hbuf, xsc, dinv,
      wpk + 0 * 8192, wpk + 8 * 8192, bx, bh, gfw, gfb, guw, gub,
      wpk + 16 * 8192, ff1b, wpk + 18 * 8192, ff2b,
      wpk + 20 * 8192, c1b, wpk + 21 * 8192, c2b, outv);

  // AggH (packed bf16 hi/lo)
  k_spmm<<<(NN + 15) / 16, 256, 0, stream>>>((const float4*)xsc, dinv, rowp, col, aggHP);

  // layer 1 + fused classifier -> outv
  k_layer<1, 0, 1><<<NB_L, 256, 0, stream>>>(
      aggXP, aggHP, hbuf, hbuf, xsc, dinv,
      wpk + 4 * 8192, wpk + 12 * 8192, bx + 256, bh + 256, gfw, gfb, guw, gub,
      wpk + 17 * 8192, ff1b + 64, wpk + 19 * 8192, ff2b + 64,
      wpk + 20 * 8192, c1b, wpk + 21 * 8192, c2b, outv);
}